// Round 1
// baseline (5435.476 us; speedup 1.0000x reference)
//
#include <hip/hip_runtime.h>
#include <math.h>

#define N_NODES   50000
#define N_EDGES   400000
#define NUM_INPUT 3703
#define NUM_DIM   256
#define NUM_OUT   6

// ---------------------------------------------------------------------------
// GEMM1: support = x @ W1.  M=50000, K=3703, N=256.
// Block = 256 threads, tile = 64 rows x 256 cols (full N in one block, so x
// is read exactly once from HBM). K-tile = 16.
// Per-thread micro-tile: 4 rows x 16 cols. A staged transposed (Alds[k][row])
// so fragment reads are ds_read_b128; B cols are tx*4 + 64*j so the float4
// reads are conflict-free (2-way aliasing only, which is free on gfx950).
// ---------------------------------------------------------------------------
__global__ __launch_bounds__(256) void gemm1_kernel(
    const float* __restrict__ x, const float* __restrict__ W1,
    float* __restrict__ support)
{
    __shared__ float Alds[16][68];    // [k][row], 64 rows padded to 68
    __shared__ float Blds[16][256];   // [k][col]

    const int t  = threadIdx.x;
    const int tx = t & 15;            // 16 col groups
    const int ty = t >> 4;            // 16 row groups
    const int m0 = blockIdx.x * 64;

    float acc[4][16];
#pragma unroll
    for (int i = 0; i < 4; ++i)
#pragma unroll
        for (int j = 0; j < 16; ++j) acc[i][j] = 0.f;

    for (int k0 = 0; k0 < NUM_INPUT; k0 += 16) {
        __syncthreads();
        // Stage A: 64 rows x 16 k, transposed into Alds[k][row].
        // x rows are only 4B-aligned (3703 % 4 != 0), so scalar loads.
#pragma unroll
        for (int c = 0; c < 4; ++c) {
            int idx = c * 256 + t;          // 0..1023
            int row = idx >> 4;             // 0..63
            int kk  = idx & 15;
            int gr = m0 + row, gk = k0 + kk;
            float v = 0.f;
            if (gr < N_NODES && gk < NUM_INPUT)
                v = x[gr * NUM_INPUT + gk];
            Alds[kk][row] = v;
        }
        // Stage B: 16 k x 256 cols of W1 (row stride 256 floats -> float4 ok).
#pragma unroll
        for (int c = 0; c < 4; ++c) {
            int idx4 = c * 256 + t;         // float4 slot 0..1023
            int row  = idx4 >> 6;           // 0..15
            int col4 = idx4 & 63;
            int gk = k0 + row;
            float4 v = make_float4(0.f, 0.f, 0.f, 0.f);
            if (gk < NUM_INPUT)
                v = *(const float4*)&W1[gk * NUM_DIM + col4 * 4];
            *(float4*)&Blds[row][col4 * 4] = v;
        }
        __syncthreads();
#pragma unroll
        for (int k = 0; k < 16; ++k) {
            float4 a   = *(const float4*)&Alds[k][ty * 4];
            float4 b0v = *(const float4*)&Blds[k][tx * 4];
            float4 b1v = *(const float4*)&Blds[k][tx * 4 + 64];
            float4 b2v = *(const float4*)&Blds[k][tx * 4 + 128];
            float4 b3v = *(const float4*)&Blds[k][tx * 4 + 192];
            const float  av[4] = {a.x, a.y, a.z, a.w};
            const float4 bv[4] = {b0v, b1v, b2v, b3v};
#pragma unroll
            for (int i = 0; i < 4; ++i) {
#pragma unroll
                for (int j = 0; j < 4; ++j) {
                    acc[i][4 * j + 0] += av[i] * bv[j].x;
                    acc[i][4 * j + 1] += av[i] * bv[j].y;
                    acc[i][4 * j + 2] += av[i] * bv[j].z;
                    acc[i][4 * j + 3] += av[i] * bv[j].w;
                }
            }
        }
    }
    // Store: col = tx*4 + 64*j + c  (contiguous float4, coalesced across tx).
#pragma unroll
    for (int i = 0; i < 4; ++i) {
        int row = m0 + ty * 4 + i;
        if (row < N_NODES) {
#pragma unroll
            for (int j = 0; j < 4; ++j) {
                float4 v = make_float4(acc[i][4 * j + 0], acc[i][4 * j + 1],
                                       acc[i][4 * j + 2], acc[i][4 * j + 3]);
                *(float4*)&support[row * NUM_DIM + tx * 4 + 64 * j] = v;
            }
        }
    }
}

// ---------------------------------------------------------------------------
// scatter1: agg[dst[e], :] += support[src[e], :] * w[e].  One block per edge,
// one thread per feature dim. Coalesced gather + coalesced atomics.
// ---------------------------------------------------------------------------
__global__ __launch_bounds__(256) void scatter1_kernel(
    const float* __restrict__ support, const int* __restrict__ src,
    const int* __restrict__ dst, const float* __restrict__ w,
    float* __restrict__ agg)
{
    int e = blockIdx.x;
    int d = threadIdx.x;
    int s = src[e];
    int tt = dst[e];
    float val = support[s * NUM_DIM + d] * w[e];
    atomicAdd(&agg[tt * NUM_DIM + d], val);
}

// ---------------------------------------------------------------------------
// act: h = leaky_relu(agg + b1), in place.
// ---------------------------------------------------------------------------
__global__ __launch_bounds__(256) void act_kernel(
    float* __restrict__ agg, const float* __restrict__ b1)
{
    int i = blockIdx.x * 256 + threadIdx.x;
    if (i >= N_NODES * NUM_DIM) return;
    float v = agg[i] + b1[i & (NUM_DIM - 1)];
    agg[i] = (v > 0.f) ? v : 0.01f * v;
}

// ---------------------------------------------------------------------------
// GEMM2: support2 = h @ W2  (256 -> 6). One wave per node; lane l holds
// h[node][4l..4l+3]; 6 dot products reduced with width-64 shuffles.
// ---------------------------------------------------------------------------
__global__ __launch_bounds__(256) void gemm2_kernel(
    const float* __restrict__ h, const float* __restrict__ W2,
    float* __restrict__ support2)
{
    int gid  = blockIdx.x * 256 + threadIdx.x;
    int node = gid >> 6;
    int lane = gid & 63;
    if (node >= N_NODES) return;
    float4 hv = *(const float4*)&h[node * NUM_DIM + lane * 4];
    const float hvv[4] = {hv.x, hv.y, hv.z, hv.w};
    float o[NUM_OUT];
#pragma unroll
    for (int j = 0; j < NUM_OUT; ++j) o[j] = 0.f;
#pragma unroll
    for (int c = 0; c < 4; ++c) {
        int k = lane * 4 + c;
#pragma unroll
        for (int j = 0; j < NUM_OUT; ++j)
            o[j] += hvv[c] * W2[k * NUM_OUT + j];
    }
#pragma unroll
    for (int j = 0; j < NUM_OUT; ++j) {
#pragma unroll
        for (int off = 32; off > 0; off >>= 1)
            o[j] += __shfl_down(o[j], off);
    }
    if (lane == 0) {
#pragma unroll
        for (int j = 0; j < NUM_OUT; ++j)
            support2[node * NUM_OUT + j] = o[j];
    }
}

// ---------------------------------------------------------------------------
// scatter2: out[dst[e], :] += support2[src[e], :] * w[e]  (6 dims/edge).
// ---------------------------------------------------------------------------
__global__ __launch_bounds__(256) void scatter2_kernel(
    const float* __restrict__ support2, const int* __restrict__ src,
    const int* __restrict__ dst, const float* __restrict__ w,
    float* __restrict__ out)
{
    int e = blockIdx.x * 256 + threadIdx.x;
    if (e >= N_EDGES) return;
    int s = src[e];
    int tt = dst[e];
    float we = w[e];
#pragma unroll
    for (int j = 0; j < NUM_OUT; ++j)
        atomicAdd(&out[tt * NUM_OUT + j], support2[s * NUM_OUT + j] * we);
}

// ---------------------------------------------------------------------------
// lsm: out = log_softmax(out + b2, axis=1), in place. One thread per node.
// ---------------------------------------------------------------------------
__global__ __launch_bounds__(256) void lsm_kernel(
    float* __restrict__ out, const float* __restrict__ b2)
{
    int n = blockIdx.x * 256 + threadIdx.x;
    if (n >= N_NODES) return;
    float v[NUM_OUT];
    float m = -1e30f;
#pragma unroll
    for (int j = 0; j < NUM_OUT; ++j) {
        v[j] = out[n * NUM_OUT + j] + b2[j];
        m = fmaxf(m, v[j]);
    }
    float s = 0.f;
#pragma unroll
    for (int j = 0; j < NUM_OUT; ++j) s += expf(v[j] - m);
    float ls = logf(s);
#pragma unroll
    for (int j = 0; j < NUM_OUT; ++j) out[n * NUM_OUT + j] = v[j] - m - ls;
}

extern "C" void kernel_launch(void* const* d_in, const int* in_sizes, int n_in,
                              void* d_out, int out_size, void* d_ws, size_t ws_size,
                              hipStream_t stream)
{
    const float* x   = (const float*)d_in[0];
    const int*   src = (const int*)  d_in[1];
    const int*   dst = (const int*)  d_in[2];
    const float* w   = (const float*)d_in[3];
    const float* W1  = (const float*)d_in[4];
    const float* b1  = (const float*)d_in[5];
    const float* W2  = (const float*)d_in[6];
    const float* b2  = (const float*)d_in[7];
    float* out = (float*)d_out;

    char* ws = (char*)d_ws;
    float* support1 = (float*)(ws);                         // 50000*256 f32 = 51.2 MB
    float* agg1     = (float*)(ws + 51200000);              // 50000*256 f32 = 51.2 MB
    float* support2 = (float*)(ws + 102400000);             // 50000*6   f32 =  1.2 MB

    // d_ws / d_out are re-poisoned to 0xAA before every launch: zero what we
    // accumulate into. (memset nodes are graph-capture safe.)
    hipMemsetAsync(agg1, 0, (size_t)N_NODES * NUM_DIM * sizeof(float), stream);
    hipMemsetAsync(out,  0, (size_t)N_NODES * NUM_OUT * sizeof(float), stream);

    gemm1_kernel<<<dim3((N_NODES + 63) / 64), 256, 0, stream>>>(x, W1, support1);
    scatter1_kernel<<<dim3(N_EDGES), 256, 0, stream>>>(support1, src, dst, w, agg1);
    act_kernel<<<dim3((N_NODES * NUM_DIM + 255) / 256), 256, 0, stream>>>(agg1, b1);
    gemm2_kernel<<<dim3((N_NODES * 64) / 256), 256, 0, stream>>>(agg1, W2, support2);
    scatter2_kernel<<<dim3((N_EDGES + 255) / 256), 256, 0, stream>>>(support2, src, dst, w, out);
    lsm_kernel<<<dim3((N_NODES + 255) / 256), 256, 0, stream>>>(out, b2);
}